// Round 1
// baseline (1020.472 us; speedup 1.0000x reference)
//
#include <hip/hip_runtime.h>

// Problem constants (from reference setup_inputs)
constexpr int BB = 16;      // batch
constexpr int D  = 2048;
constexpr int U  = 37;
constexpr long long DD = (long long)D * D;   // 4,194,304 elements, 16 MB

constexpr int TPB = 256;
constexpr int C   = 1024;                         // chunks over (i,j); chunk = 2 rows
constexpr int F4_PER_BLOCK  = (int)(DD / 4 / C);  // 1024 float4 per chunk (16 KB)
constexpr int F4_PER_THREAD = F4_PER_BLOCK / TPB; // 4 float4 per thread

// ws layout: partial[U][C] floats, then wdiag[U][D] floats  (total ~455 KB)

// Kernel A: for chunk c,
//   partial[u][c] = sum_{ij in chunk} relu(matrix[ij]) * weight[u][ij]
//   wdiag[u][i]   = weight[u][i][i]  for the 2 diagonal rows i = 2c, 2c+1
// Pure streaming u-loop: 37 per-thread accumulators (fully unrolled -> VGPRs,
// no per-u shuffle bubbles); one deferred block-reduce at the end.
__global__ __launch_bounds__(TPB, 4) void base_diag_kernel(
    const float* __restrict__ matrix,
    const float* __restrict__ weight,
    float* __restrict__ partial,   // (U, C)
    float* __restrict__ wdiag)     // (U, D)
{
    const int c = blockIdx.x;
    const long long base4 = (long long)c * F4_PER_BLOCK + threadIdx.x;
    const float4* __restrict__ m4 = (const float4*)matrix;

    // relu(matrix chunk) cached in registers: 4 x float4 = 16 VGPRs
    float4 m[F4_PER_THREAD];
#pragma unroll
    for (int it = 0; it < F4_PER_THREAD; ++it) {
        float4 t = m4[base4 + (long long)it * TPB];
        m[it].x = fmaxf(t.x, 0.f);
        m[it].y = fmaxf(t.y, 0.f);
        m[it].z = fmaxf(t.z, 0.f);
        m[it].w = fmaxf(t.w, 0.f);
    }

    float acc[U];
#pragma unroll
    for (int u = 0; u < U; ++u) acc[u] = 0.f;

#pragma unroll
    for (int u = 0; u < U; ++u) {
        const float4* __restrict__ w4 = (const float4*)(weight + (long long)u * DD);
        // diagonal extraction: chunk covers rows 2c and 2c+1; the cache lines
        // holding (i,i) are being streamed by this block anyway -> L1/L2 hit.
        if (threadIdx.x < 2) {
            const int i = 2 * c + (int)threadIdx.x;
            wdiag[u * D + i] = weight[(long long)u * DD + (long long)i * (D + 1)];
        }
#pragma unroll
        for (int it = 0; it < F4_PER_THREAD; ++it) {
            float4 w = w4[base4 + (long long)it * TPB];
            acc[u] = fmaf(m[it].x, w.x, acc[u]);
            acc[u] = fmaf(m[it].y, w.y, acc[u]);
            acc[u] = fmaf(m[it].z, w.z, acc[u]);
            acc[u] = fmaf(m[it].w, w.w, acc[u]);
        }
    }

    // Deferred block reduce of all 37 accumulators (37 independent shuffle
    // chains -> latency hidden by ILP; runs once per block, off the stream path)
    __shared__ float lpart[U];
    if (threadIdx.x < U) lpart[threadIdx.x] = 0.f;
    __syncthreads();
#pragma unroll
    for (int u = 0; u < U; ++u) {
#pragma unroll
        for (int off = 32; off > 0; off >>= 1)
            acc[u] += __shfl_down(acc[u], off, 64);
    }
    if ((threadIdx.x & 63) == 0) {
#pragma unroll
        for (int u = 0; u < U; ++u)
            atomicAdd(&lpart[u], acc[u]);   // 4 waves x 37, once per block
    }
    __syncthreads();
    if (threadIdx.x < U)
        partial[(long long)threadIdx.x * C + c] = lpart[threadIdx.x];
}

// Kernel B: out[b,u] = bias[u] + sum_c partial[u,c]
//                    + sum_i (relu(m_ii * x_bi) - relu(m_ii)) * wdiag[u,i]
// wdiag is compact (coalesced); only matrix diag is scattered (128 KB, L2-hot).
__global__ __launch_bounds__(TPB) void finish_kernel(
    const float* __restrict__ inputs,
    const float* __restrict__ matrix,
    const float* __restrict__ bias,
    const float* __restrict__ partial,
    const float* __restrict__ wdiag,
    float* __restrict__ out)
{
    const int u = blockIdx.x;
    const int b = blockIdx.y;

    float acc = 0.f;
    for (int i = threadIdx.x; i < D; i += TPB) {
        float mm = matrix[(long long)i * (D + 1)];
        float wd = wdiag[u * D + i];
        float x  = inputs[b * D + i];
        acc += (fmaxf(mm * x, 0.f) - fmaxf(mm, 0.f)) * wd;
    }
    for (int cc = threadIdx.x; cc < C; cc += TPB)
        acc += partial[(long long)u * C + cc];

#pragma unroll
    for (int off = 32; off > 0; off >>= 1)
        acc += __shfl_down(acc, off, 64);

    __shared__ float smem[TPB / 64];
    if ((threadIdx.x & 63) == 0) smem[threadIdx.x >> 6] = acc;
    __syncthreads();
    if (threadIdx.x == 0) {
        float t = 0.f;
#pragma unroll
        for (int w = 0; w < TPB / 64; ++w) t += smem[w];
        out[b * U + u] = t + bias[u];
    }
}

extern "C" void kernel_launch(void* const* d_in, const int* in_sizes, int n_in,
                              void* d_out, int out_size, void* d_ws, size_t ws_size,
                              hipStream_t stream) {
    const float* inputs = (const float*)d_in[0];   // (B, D)
    const float* matrix = (const float*)d_in[1];   // (D, D)
    const float* weight = (const float*)d_in[2];   // (U, D, D)
    const float* bias   = (const float*)d_in[3];   // (U,)
    float* out     = (float*)d_out;                // (B, U) f32
    float* partial = (float*)d_ws;                 // (U, C)
    float* wdiag   = (float*)d_ws + (long long)U * C;  // (U, D)

    base_diag_kernel<<<dim3(C), TPB, 0, stream>>>(matrix, weight, partial, wdiag);
    finish_kernel<<<dim3(U, BB), TPB, 0, stream>>>(inputs, matrix, bias,
                                                   partial, wdiag, out);
}

// Round 2
// 805.663 us; speedup vs baseline: 1.2666x; 1.2666x over previous
//
#include <hip/hip_runtime.h>

// Problem constants (from reference setup_inputs)
constexpr int BB = 16;      // batch
constexpr int D  = 2048;
constexpr int U  = 37;
constexpr long long DD = (long long)D * D;   // 4,194,304 elements, 16 MB

constexpr int TPB = 256;
constexpr int C   = 1024;                         // chunks over (i,j); chunk = 2 rows
constexpr int F4_PER_BLOCK  = (int)(DD / 4 / C);  // 1024 float4 per chunk (16 KB)
constexpr int F4_PER_THREAD = F4_PER_BLOCK / TPB; // 4 float4 per thread
constexpr int NGRP = 5;                           // u-groups: 8,8,8,8,5

// ws layout: partial[U][C] floats, then wdiag[U][D] floats (~455 KB)

// Stream G weight planes [u0, u0+G) through the register-resident matrix chunk.
// G is a template param so acc[] is statically indexed (registers, never scratch).
template<int G>
__device__ __forceinline__ void stream_group(
    const int u0, const int c, const long long base4,
    const float4 (&m)[F4_PER_THREAD],
    const float* __restrict__ weight,
    float* __restrict__ partial)
{
    float acc[G];
#pragma unroll
    for (int g = 0; g < G; ++g) acc[g] = 0.f;

#pragma unroll
    for (int g = 0; g < G; ++g) {
        const float4* __restrict__ w4 =
            (const float4*)(weight + (long long)(u0 + g) * DD);
#pragma unroll
        for (int it = 0; it < F4_PER_THREAD; ++it) {
            const float4 w = w4[base4 + (long long)it * TPB];
            acc[g] = fmaf(m[it].x, w.x, acc[g]);
            acc[g] = fmaf(m[it].y, w.y, acc[g]);
            acc[g] = fmaf(m[it].z, w.z, acc[g]);
            acc[g] = fmaf(m[it].w, w.w, acc[g]);
        }
    }

    // G independent shuffle chains -> latency hidden by ILP; once per block.
#pragma unroll
    for (int g = 0; g < G; ++g)
#pragma unroll
        for (int off = 32; off > 0; off >>= 1)
            acc[g] += __shfl_down(acc[g], off, 64);

    __shared__ float lpart[G];
    if (threadIdx.x < G) lpart[threadIdx.x] = 0.f;
    __syncthreads();
    if ((threadIdx.x & 63) == 0) {
#pragma unroll
        for (int g = 0; g < G; ++g)
            atomicAdd(&lpart[g], acc[g]);   // 4 waves x G, once per block
    }
    __syncthreads();
    if (threadIdx.x < G)
        partial[(long long)(u0 + threadIdx.x) * C + c] = lpart[threadIdx.x];
}

// Kernel A: block (grp, c) computes partial[u, c] for u in its group.
// grp is the FAST grid dim so the 5 blocks sharing a matrix chunk are
// dispatched back-to-back -> chunk re-reads hit L2/L3, not HBM.
__global__ __launch_bounds__(TPB, 4) void base_kernel(
    const float* __restrict__ matrix,
    const float* __restrict__ weight,
    float* __restrict__ partial,   // (U, C)
    float* __restrict__ wdiag)     // (U, D)
{
    const int grp = blockIdx.x;
    const int c   = blockIdx.y;
    const long long base4 = (long long)c * F4_PER_BLOCK + threadIdx.x;
    const float4* __restrict__ m4 = (const float4*)matrix;

    // relu(matrix chunk) in registers: 4 x float4 = 16 VGPRs
    float4 m[F4_PER_THREAD];
#pragma unroll
    for (int it = 0; it < F4_PER_THREAD; ++it) {
        float4 t = m4[base4 + (long long)it * TPB];
        m[it].x = fmaxf(t.x, 0.f);
        m[it].y = fmaxf(t.y, 0.f);
        m[it].z = fmaxf(t.z, 0.f);
        m[it].w = fmaxf(t.w, 0.f);
    }

    // Diagonal extraction, hoisted out of the streaming loop; group 0 only.
    // Chunk c covers rows 2c, 2c+1 -> this block owns 2 diag elements per u.
    if (grp == 0 && threadIdx.x < 2 * U) {
        const int u = threadIdx.x >> 1;
        const int i = 2 * c + (threadIdx.x & 1);
        wdiag[u * D + i] = weight[(long long)u * DD + (long long)i * (D + 1)];
    }

    if (grp < 4) stream_group<8>(grp * 8, c, base4, m, weight, partial);
    else         stream_group<5>(32,      c, base4, m, weight, partial);
}

// Kernel B: out[b,u] = bias[u] + sum_c partial[u,c]
//                    + sum_i (relu(m_ii * x_bi) - relu(m_ii)) * wdiag[u,i]
__global__ __launch_bounds__(TPB) void finish_kernel(
    const float* __restrict__ inputs,
    const float* __restrict__ matrix,
    const float* __restrict__ bias,
    const float* __restrict__ partial,
    const float* __restrict__ wdiag,
    float* __restrict__ out)
{
    const int u = blockIdx.x;
    const int b = blockIdx.y;

    float acc = 0.f;
    for (int i = threadIdx.x; i < D; i += TPB) {
        float mm = matrix[(long long)i * (D + 1)];
        float wd = wdiag[u * D + i];
        float x  = inputs[b * D + i];
        acc += (fmaxf(mm * x, 0.f) - fmaxf(mm, 0.f)) * wd;
    }
    for (int cc = threadIdx.x; cc < C; cc += TPB)
        acc += partial[(long long)u * C + cc];

#pragma unroll
    for (int off = 32; off > 0; off >>= 1)
        acc += __shfl_down(acc, off, 64);

    __shared__ float smem[TPB / 64];
    if ((threadIdx.x & 63) == 0) smem[threadIdx.x >> 6] = acc;
    __syncthreads();
    if (threadIdx.x == 0) {
        float t = 0.f;
#pragma unroll
        for (int w = 0; w < TPB / 64; ++w) t += smem[w];
        out[b * U + u] = t + bias[u];
    }
}

extern "C" void kernel_launch(void* const* d_in, const int* in_sizes, int n_in,
                              void* d_out, int out_size, void* d_ws, size_t ws_size,
                              hipStream_t stream) {
    const float* inputs = (const float*)d_in[0];   // (B, D)
    const float* matrix = (const float*)d_in[1];   // (D, D)
    const float* weight = (const float*)d_in[2];   // (U, D, D)
    const float* bias   = (const float*)d_in[3];   // (U,)
    float* out     = (float*)d_out;                // (B, U) f32
    float* partial = (float*)d_ws;                 // (U, C)
    float* wdiag   = (float*)d_ws + (long long)U * C;  // (U, D)

    base_kernel<<<dim3(NGRP, C), TPB, 0, stream>>>(matrix, weight, partial, wdiag);
    finish_kernel<<<dim3(U, BB), TPB, 0, stream>>>(inputs, matrix, bias,
                                                   partial, wdiag, out);
}

// Round 3
// 783.980 us; speedup vs baseline: 1.3017x; 1.0277x over previous
//
#include <hip/hip_runtime.h>

// Problem constants (from reference setup_inputs)
constexpr int BB = 16;      // batch
constexpr int D  = 2048;
constexpr int U  = 37;
constexpr long long DD = (long long)D * D;   // 4,194,304 elements, 16 MB

constexpr int TPB = 256;
constexpr int C   = 512;                          // chunks; chunk = 4 matrix rows, 32 KB
constexpr int F4B = (int)(DD / 4 / C);            // 2048 float4 per chunk
constexpr int F4T = F4B / TPB;                    // 8 float4 per thread
constexpr int NGRP = 5;                           // u-groups: 8,8,8,8,5

// ws layout: partial[U][C] floats, then wdiag[U][D] floats

using f4 = __attribute__((ext_vector_type(4))) float;

// Nontemporal stream of one plane's chunk into a named register buffer.
// Weight is read exactly once chip-wide: bypassing L2/L3 allocation avoids
// evicting the (reused) matrix and lets the counted-vmcnt pipeline below work
// on a pure HBM stream.
__device__ __forceinline__ void load_plane(f4 (&buf)[F4T],
                                           const f4* __restrict__ w4,
                                           const long long base4) {
#pragma unroll
    for (int it = 0; it < F4T; ++it)
        buf[it] = __builtin_nontemporal_load(&w4[base4 + (long long)it * TPB]);
}

__device__ __forceinline__ void fma_plane(float& acc, const f4 (&m)[F4T],
                                          const f4 (&buf)[F4T]) {
#pragma unroll
    for (int it = 0; it < F4T; ++it) {
        acc = fmaf(m[it].x, buf[it].x, acc);
        acc = fmaf(m[it].y, buf[it].y, acc);
        acc = fmaf(m[it].z, buf[it].z, acc);
        acc = fmaf(m[it].w, buf[it].w, acc);
    }
}

// Stream G weight planes [u0, u0+G) through the register-resident matrix chunk
// with a 2-deep cross-plane pipeline: plane g+1's loads are issued BEFORE
// plane g is consumed, so each wave keeps ~16 KB in flight continuously
// (counted vmcnt wait) instead of draining per plane. Buffers are named
// (bufA/bufB) with a manual 2-unroll -> all indexing static, no scratch.
template<int G>
__device__ __forceinline__ void stream_group(
    const int u0, const int c, const long long base4,
    const f4 (&m)[F4T],
    const float* __restrict__ weight,
    float* __restrict__ partial)
{
    float acc[G];
#pragma unroll
    for (int g = 0; g < G; ++g) acc[g] = 0.f;

    f4 bufA[F4T], bufB[F4T];
    load_plane(bufA, (const f4*)(weight + (long long)u0 * DD), base4);

#pragma unroll
    for (int g = 0; g < G; g += 2) {
        if (g + 1 < G)
            load_plane(bufB, (const f4*)(weight + (long long)(u0 + g + 1) * DD), base4);
        fma_plane(acc[g], m, bufA);
        if (g + 2 < G)
            load_plane(bufA, (const f4*)(weight + (long long)(u0 + g + 2) * DD), base4);
        if (g + 1 < G)
            fma_plane(acc[g + 1], m, bufB);
    }

    // G independent shuffle chains -> latency hidden by ILP; once per block.
#pragma unroll
    for (int g = 0; g < G; ++g)
#pragma unroll
        for (int off = 32; off > 0; off >>= 1)
            acc[g] += __shfl_down(acc[g], off, 64);

    __shared__ float lpart[G];
    if (threadIdx.x < G) lpart[threadIdx.x] = 0.f;
    __syncthreads();
    if ((threadIdx.x & 63) == 0) {
#pragma unroll
        for (int g = 0; g < G; ++g)
            atomicAdd(&lpart[g], acc[g]);   // 4 waves x G, once per block
    }
    __syncthreads();
    if (threadIdx.x < G)
        partial[(long long)(u0 + threadIdx.x) * C + c] = lpart[threadIdx.x];
}

// Kernel A: block (grp, c) computes partial[u, c] for u in its group.
// grp is the FAST grid dim so blocks sharing a matrix chunk are dispatched
// close together -> chunk re-reads hit L3 (matrix stays cacheable; weight
// loads are nontemporal and don't evict it).
__global__ __launch_bounds__(TPB, 2) void base_kernel(
    const float* __restrict__ matrix,
    const float* __restrict__ weight,
    float* __restrict__ partial,   // (U, C)
    float* __restrict__ wdiag)     // (U, D)
{
    const int grp = blockIdx.x;
    const int c   = blockIdx.y;
    const long long base4 = (long long)c * F4B + threadIdx.x;
    const f4* __restrict__ m4 = (const f4*)matrix;

    // relu(matrix chunk) in registers: 8 x float4 = 32 VGPRs
    f4 m[F4T];
#pragma unroll
    for (int it = 0; it < F4T; ++it) {
        f4 t = m4[base4 + (long long)it * TPB];
        m[it].x = fmaxf(t.x, 0.f);
        m[it].y = fmaxf(t.y, 0.f);
        m[it].z = fmaxf(t.z, 0.f);
        m[it].w = fmaxf(t.w, 0.f);
    }

    // Diagonal extraction, group 0 only. Chunk c covers rows 4c..4c+3.
    if (grp == 0 && threadIdx.x < 4 * U) {
        const int u = threadIdx.x >> 2;
        const int i = 4 * c + (threadIdx.x & 3);
        wdiag[u * D + i] = weight[(long long)u * DD + (long long)i * (D + 1)];
    }

    if (grp < 4) stream_group<8>(grp * 8, c, base4, m, weight, partial);
    else         stream_group<5>(32,      c, base4, m, weight, partial);
}

// Kernel B: out[b,u] = bias[u] + sum_c partial[u,c]
//                    + sum_i (relu(m_ii * x_bi) - relu(m_ii)) * wdiag[u,i]
__global__ __launch_bounds__(TPB) void finish_kernel(
    const float* __restrict__ inputs,
    const float* __restrict__ matrix,
    const float* __restrict__ bias,
    const float* __restrict__ partial,
    const float* __restrict__ wdiag,
    float* __restrict__ out)
{
    const int u = blockIdx.x;
    const int b = blockIdx.y;

    float acc = 0.f;
    for (int i = threadIdx.x; i < D; i += TPB) {
        float mm = matrix[(long long)i * (D + 1)];
        float wd = wdiag[u * D + i];
        float x  = inputs[b * D + i];
        acc += (fmaxf(mm * x, 0.f) - fmaxf(mm, 0.f)) * wd;
    }
    for (int cc = threadIdx.x; cc < C; cc += TPB)
        acc += partial[(long long)u * C + cc];

#pragma unroll
    for (int off = 32; off > 0; off >>= 1)
        acc += __shfl_down(acc, off, 64);

    __shared__ float smem[TPB / 64];
    if ((threadIdx.x & 63) == 0) smem[threadIdx.x >> 6] = acc;
    __syncthreads();
    if (threadIdx.x == 0) {
        float t = 0.f;
#pragma unroll
        for (int w = 0; w < TPB / 64; ++w) t += smem[w];
        out[b * U + u] = t + bias[u];
    }
}

extern "C" void kernel_launch(void* const* d_in, const int* in_sizes, int n_in,
                              void* d_out, int out_size, void* d_ws, size_t ws_size,
                              hipStream_t stream) {
    const float* inputs = (const float*)d_in[0];   // (B, D)
    const float* matrix = (const float*)d_in[1];   // (D, D)
    const float* weight = (const float*)d_in[2];   // (U, D, D)
    const float* bias   = (const float*)d_in[3];   // (U,)
    float* out     = (float*)d_out;                // (B, U) f32
    float* partial = (float*)d_ws;                 // (U, C)
    float* wdiag   = (float*)d_ws + (long long)U * C;  // (U, D)

    base_kernel<<<dim3(NGRP, C), TPB, 0, stream>>>(matrix, weight, partial, wdiag);
    finish_kernel<<<dim3(U, BB), TPB, 0, stream>>>(inputs, matrix, bias,
                                                   partial, wdiag, out);
}